// Round 5
// baseline (414.366 us; speedup 1.0000x reference)
//
#include <hip/hip_runtime.h>
#include <cfloat>
#include <cmath>

#define B_   8
#define N_   8192
#define S_   2048
#define C1_  128
#define C2_  256
#define T_   256
#define CIN_ 384
#define CO_  256

#define KCH  8           // knn S-chunks
#define KCS  (S_ / KCH)  // 256 candidates per chunk
#define KQB  512         // queries per knn block (256 thr x 2 queries)

typedef __attribute__((ext_vector_type(8))) short short8;
typedef __attribute__((ext_vector_type(4))) float f32x4;

// ---------- helpers ----------
__device__ __forceinline__ float bf2f(unsigned short u) {
    union { unsigned int i; float f; } v; v.i = ((unsigned int)u) << 16; return v.f;
}
__device__ __forceinline__ unsigned short f2bf(float f) {
    union { float f; unsigned int i; } v; v.f = f;
    unsigned int i = v.i;
    unsigned int r = i + 0x7FFFu + ((i >> 16) & 1u);   // RNE
    return (unsigned short)(r >> 16);
}
__device__ __forceinline__ float gelu_f(float x) {
    return 0.5f * x * (1.0f + erff(x * 0.70710678118654752440f));
}
__device__ __forceinline__ void async16(const void* g, void* l) {
    __builtin_amdgcn_global_load_lds((const __attribute__((address_space(1))) void*)g,
                                     (__attribute__((address_space(3))) void*)l, 16, 0, 0);
}

// ---------- ws layout (bytes) ----------
#define OFF_TE1   0u
#define OFF_TE2   16384u
#define OFF_BN1   28672u      // scale1(1024) shift1(1024)
#define OFF_BN2   30720u
#define OFF_IDX   32768u      // 65536*3*4 = 786432
#define OFF_WTS   819200u     // 786432
#define OFF_WC1   1605632u    // 98304*2
#define OFF_WC2   1802240u    // 65536*2  (ends 1933312)
#define OFF_P2T   2097152u    // 8*2048*256*2 = 8388608 (bf16)
#define OFF_X1    10485760u   // 8*8192*384*2 = 50331648 (bf16; Z + knn partials reuse)
#define OFF_Y     60817408u   // 8*8192*256*2 = 33554432 (bf16)
// transient tenants:
#define OFF_PD    OFF_X1                    // knn dist partials  6291456 (dead before X1 write)
#define OFF_PI    (OFF_X1 + 6291456u)       // knn idx partials   6291456
#define OFF_PS    OFF_P2T                   // gemm stat partials: 1024*256*4 = 1 MB (p2t dead)
#define OFF_PQ    (OFF_P2T + 1048576u)      // 1 MB

// ---------- weight fp32 -> bf16 ----------
__global__ __launch_bounds__(256) void wcvt_kernel(
    const float* __restrict__ w1, const float* __restrict__ w2,
    unsigned short* __restrict__ o1, unsigned short* __restrict__ o2)
{
    int g = blockIdx.x * 256 + threadIdx.x;          // grid 384 blocks
    o1[g] = f2bf(w1[g]);
    if (g < CO_ * CO_) o2[g] = f2bf(w2[g]);
}

// ---------- te1/te2 ----------
__global__ __launch_bounds__(640) void te_kernel(
    const float* __restrict__ t_embed,
    const float* __restrict__ w_t1, const float* __restrict__ b_t1,
    const float* __restrict__ w_t2, const float* __restrict__ b_t2,
    float* __restrict__ te1, float* __restrict__ te2)
{
    __shared__ float gt[T_];
    int b = blockIdx.x, t = threadIdx.x;
    if (t < T_) gt[t] = gelu_f(t_embed[b * T_ + t]);
    __syncthreads();
    if (t < CIN_) {
        const float* w = w_t1 + t * T_;
        float s = 0.f;
        for (int k = 0; k < T_; ++k) s += gt[k] * w[k];
        te1[b * CIN_ + t] = s + b_t1[t];
    } else {
        int o = t - CIN_;
        const float* w = w_t2 + o * T_;
        float s = 0.f;
        for (int k = 0; k < T_; ++k) s += gt[k] * w[k];
        te2[b * CO_ + o] = s + b_t2[o];
    }
}

// ---------- 3-NN partials: per S-chunk top-3, branch-free cswap network ----------
__global__ __launch_bounds__(256) void knn_part_kernel(
    const float* __restrict__ xyz1, const float* __restrict__ xyz2,
    float* __restrict__ pd, int* __restrict__ pi)
{
    __shared__ float4 sp[KCS];   // 4 KB
    int b = blockIdx.z, ch = blockIdx.y, tid = threadIdx.x;
    int s0 = ch * KCS;
    {
        int gs = s0 + tid;
        float x = xyz2[(b * S_ + gs) * 3 + 0];
        float y = xyz2[(b * S_ + gs) * 3 + 1];
        float z = xyz2[(b * S_ + gs) * 3 + 2];
        sp[tid] = make_float4(x, y, z, x * x + y * y + z * z);
    }
    __syncthreads();

    float nx[2], ny[2], nz[2], nn[2];
    float d1[2], d2[2], d3[2];
    int   i1[2], i2[2], i3[2];
    #pragma unroll
    for (int qq = 0; qq < 2; ++qq) {
        int n = blockIdx.x * KQB + qq * 256 + tid;
        float x1 = xyz1[(b * N_ + n) * 3 + 0];
        float y1 = xyz1[(b * N_ + n) * 3 + 1];
        float z1 = xyz1[(b * N_ + n) * 3 + 2];
        nn[qq] = x1 * x1 + y1 * y1 + z1 * z1;
        nx[qq] = -2.0f * x1; ny[qq] = -2.0f * y1; nz[qq] = -2.0f * z1;
        d1[qq] = FLT_MAX; d2[qq] = FLT_MAX; d3[qq] = FLT_MAX;
        i1[qq] = 0; i2[qq] = 0; i3[qq] = 0;
    }

    for (int s = 0; s < KCS; s += 4) {
        #pragma unroll
        for (int u = 0; u < 4; ++u) {
            float4 p = sp[s + u];
            int gi = s0 + s + u;
            #pragma unroll
            for (int qq = 0; qq < 2; ++qq) {
                // d = nn + |p|^2 - 2<q,p>, as 1 add + 3 fma
                float d = fmaf(nx[qq], p.x,
                          fmaf(ny[qq], p.y,
                          fmaf(nz[qq], p.z, nn[qq] + p.w)));
                // sorted-triple insert (d1<=d2<=d3), strict '<' keeps earliest idx on ties
                bool c3 = d < d3[qq];
                i3[qq] = c3 ? gi : i3[qq];
                d3[qq] = fminf(d3[qq], d);
                bool c2 = d3[qq] < d2[qq];
                float lo2 = fminf(d2[qq], d3[qq]);
                float hi2 = fmaxf(d2[qq], d3[qq]);
                int t2 = c2 ? i3[qq] : i2[qq];
                int t3 = c2 ? i2[qq] : i3[qq];
                d2[qq] = lo2; d3[qq] = hi2; i2[qq] = t2; i3[qq] = t3;
                bool c1 = d2[qq] < d1[qq];
                float lo1 = fminf(d1[qq], d2[qq]);
                float hi1 = fmaxf(d1[qq], d2[qq]);
                int t1  = c1 ? i2[qq] : i1[qq];
                int t2b = c1 ? i1[qq] : i2[qq];
                d1[qq] = lo1; d2[qq] = hi1; i1[qq] = t1; i2[qq] = t2b;
            }
        }
    }

    #pragma unroll
    for (int qq = 0; qq < 2; ++qq) {
        int n = blockIdx.x * KQB + qq * 256 + tid;
        size_t pb = (((size_t)b * KCH + ch) * N_ + n) * 3;
        pd[pb + 0] = d1[qq]; pd[pb + 1] = d2[qq]; pd[pb + 2] = d3[qq];
        pi[pb + 0] = i1[qq]; pi[pb + 1] = i2[qq]; pi[pb + 2] = i3[qq];
    }
}

// ---------- merge chunk partials -> idx/wts ----------
__global__ __launch_bounds__(256) void knn_merge_kernel(
    const float* __restrict__ pd, const int* __restrict__ pi,
    int* __restrict__ idx, float* __restrict__ wts)
{
    int g = blockIdx.x * 256 + threadIdx.x;   // 65536
    int b = g >> 13, n = g & (N_ - 1);
    float d1 = FLT_MAX, d2 = FLT_MAX, d3 = FLT_MAX;
    int   i1 = 0, i2 = 0, i3 = 0;
    for (int ch = 0; ch < KCH; ++ch) {
        size_t pb = (((size_t)b * KCH + ch) * N_ + n) * 3;
        #pragma unroll
        for (int k = 0; k < 3; ++k) {
            float d = pd[pb + k];
            int   s = pi[pb + k];
            if (d < d3) {
                if (d < d2) {
                    d3 = d2; i3 = i2;
                    if (d < d1) { d2 = d1; i2 = i1; d1 = d; i1 = s; }
                    else        { d2 = d;  i2 = s; }
                } else { d3 = d; i3 = s; }
            }
        }
    }
    float r1 = 1.0f / (d1 + 1e-8f);
    float r2 = 1.0f / (d2 + 1e-8f);
    float r3 = 1.0f / (d3 + 1e-8f);
    float rs = 1.0f / (r1 + r2 + r3);
    size_t base = (size_t)g * 3;
    idx[base] = i1; idx[base + 1] = i2; idx[base + 2] = i3;
    wts[base] = r1 * rs; wts[base + 1] = r2 * rs; wts[base + 2] = r3 * rs;
}

// ---------- transpose points2 (B,C2,S) fp32 -> (B,S,C2) bf16 ----------
__global__ __launch_bounds__(256) void transpose_p2(
    const float* __restrict__ p2, unsigned short* __restrict__ p2t)
{
    __shared__ unsigned short tile[32][33];
    int b = blockIdx.z, s0 = blockIdx.x * 32, c0 = blockIdx.y * 32;
    #pragma unroll
    for (int j = 0; j < 4; ++j) {
        int c = threadIdx.y + j * 8;
        tile[c][threadIdx.x] = f2bf(p2[((size_t)b * C2_ + c0 + c) * S_ + s0 + threadIdx.x]);
    }
    __syncthreads();
    #pragma unroll
    for (int j = 0; j < 4; ++j) {
        int s = threadIdx.y + j * 8;
        p2t[((size_t)b * S_ + s0 + s) * C2_ + c0 + threadIdx.x] = tile[threadIdx.x][s];
    }
}

// ---------- build X1 (B,N,384) bf16, k-contiguous ----------
__global__ __launch_bounds__(384) void build_x1_kernel(
    const float* __restrict__ points1,            // (B,128,N) fp32
    const unsigned short* __restrict__ p2t,       // (B,S,256) bf16
    const int* __restrict__ idx, const float* __restrict__ wts,
    const float* __restrict__ te1,                // (B,384) f32
    unsigned short* __restrict__ X1)
{
    int b = blockIdx.y;
    int tx = threadIdx.x & 127;
    int ty = threadIdx.x >> 7;
    int n = blockIdx.x * 128 + tx;
    unsigned short* xr = X1 + ((size_t)b * N_ + n) * CIN_;
    const float* te = te1 + b * CIN_;

    if (ty == 0) {
        #pragma unroll
        for (int c = 0; c < C1_; c += 8) {
            union { short8 v; unsigned short u[8]; } pk;
            #pragma unroll
            for (int jj = 0; jj < 8; ++jj) {
                float v = points1[((size_t)b * C1_ + c + jj) * N_ + n] + te[c + jj];
                pk.u[jj] = f2bf(v);
            }
            *(short8*)&xr[c] = pk.v;
        }
    } else {
        size_t base3 = ((size_t)b * N_ + n) * 3;
        int j0 = idx[base3], j1 = idx[base3 + 1], j2 = idx[base3 + 2];
        float w0 = wts[base3], w1 = wts[base3 + 1], w2 = wts[base3 + 2];
        int cbase = (ty - 1) * 128;
        const unsigned short* r0 = p2t + ((size_t)b * S_ + j0) * C2_ + cbase;
        const unsigned short* r1 = p2t + ((size_t)b * S_ + j1) * C2_ + cbase;
        const unsigned short* r2 = p2t + ((size_t)b * S_ + j2) * C2_ + cbase;
        #pragma unroll
        for (int c = 0; c < 128; c += 8) {
            union { short8 v; unsigned short u[8]; } a0, a1, a2, pk;
            a0.v = *(const short8*)&r0[c];
            a1.v = *(const short8*)&r1[c];
            a2.v = *(const short8*)&r2[c];
            #pragma unroll
            for (int jj = 0; jj < 8; ++jj) {
                float v = w0 * bf2f(a0.u[jj]) + w1 * bf2f(a1.u[jj]) + w2 * bf2f(a2.u[jj])
                        + te[C1_ + cbase + c + jj];
                pk.u[jj] = f2bf(v);
            }
            *(short8*)&xr[C1_ + cbase + c] = pk.v;
        }
    }
}

// ---------- GEMM (m97-style, B^T input) + fused per-block BN-stat partials ----------
// MODE 0: out[b][n][o] bf16.  MODE 1: out[b][o][n] bf16.
// Partials: psum/psq [1024][256]; row p = (b*64 + blockIdx.x)*2 + wm. No atomics.
template <int K, int MODE>
__global__ __launch_bounds__(256) void gemm_bt(
    const unsigned short* __restrict__ A,
    const unsigned short* __restrict__ X,
    const float* __restrict__ bias,
    unsigned short* __restrict__ out,
    float* __restrict__ psum, float* __restrict__ psq)
{
    __shared__ unsigned short sA[128 * 64];
    __shared__ unsigned short sB[128 * 64];
    const int tid = threadIdx.x;
    const int lane = tid & 63, wave = tid >> 6;
    const int wo = wave >> 1, wm = wave & 1;
    const int quad = lane >> 4, col = lane & 15;
    const int b = blockIdx.z;
    const int o0 = blockIdx.y * 128;
    const int n0 = blockIdx.x * 128;
    const unsigned short* Xb = X + (size_t)b * N_ * K;
    const int prow = ((b << 6) + blockIdx.x) * 2 + wm;

    f32x4 acc[4][4];
    #pragma unroll
    for (int i = 0; i < 4; ++i)
        #pragma unroll
        for (int j = 0; j < 4; ++j) acc[i][j] = (f32x4){0.f, 0.f, 0.f, 0.f};

    for (int k0 = 0; k0 < K; k0 += 64) {
        #pragma unroll
        for (int i = 0; i < 4; ++i) {
            int chunk = i * 256 + tid;
            int row = chunk >> 3, c8 = chunk & 7;
            async16(&A [(o0 + row) * K + k0 + c8 * 8], &sA[chunk * 8]);
            async16(&Xb[(size_t)(n0 + row) * K + k0 + c8 * 8], &sB[chunk * 8]);
        }
        __syncthreads();
        #pragma unroll
        for (int kk = 0; kk < 64; kk += 32) {
            short8 af[4], bfr[4];
            #pragma unroll
            for (int i = 0; i < 4; ++i)
                af[i] = *(const short8*)&sA[(wo * 64 + i * 16 + col) * 64 + kk + quad * 8];
            #pragma unroll
            for (int j = 0; j < 4; ++j)
                bfr[j] = *(const short8*)&sB[(wm * 64 + j * 16 + col) * 64 + kk + quad * 8];
            #pragma unroll
            for (int i = 0; i < 4; ++i)
                #pragma unroll
                for (int j = 0; j < 4; ++j)
                    acc[i][j] = __builtin_amdgcn_mfma_f32_16x16x32_bf16(af[i], bfr[j], acc[i][j], 0, 0, 0);
        }
        __syncthreads();
    }

    #pragma unroll
    for (int i = 0; i < 4; ++i) {
        int oo = o0 + wo * 64 + i * 16 + quad * 4;
        float bv0 = bias[oo + 0], bv1 = bias[oo + 1];
        float bv2 = bias[oo + 2], bv3 = bias[oo + 3];
        float s0 = 0.f, s1 = 0.f, s2 = 0.f, s3 = 0.f;
        float q0 = 0.f, q1 = 0.f, q2 = 0.f, q3 = 0.f;
        #pragma unroll
        for (int j = 0; j < 4; ++j) {
            int nn = n0 + wm * 64 + j * 16 + col;
            float v0 = acc[i][j][0] + bv0, v1 = acc[i][j][1] + bv1;
            float v2 = acc[i][j][2] + bv2, v3 = acc[i][j][3] + bv3;
            s0 += v0; q0 += v0 * v0; s1 += v1; q1 += v1 * v1;
            s2 += v2; q2 += v2 * v2; s3 += v3; q3 += v3 * v3;
            if (MODE == 0) {
                union { unsigned short u[4]; uint2 p; } pk;
                pk.u[0] = f2bf(v0); pk.u[1] = f2bf(v1);
                pk.u[2] = f2bf(v2); pk.u[3] = f2bf(v3);
                *(uint2*)&out[((size_t)b * N_ + nn) * CO_ + oo] = pk.p;
            } else {
                out[((size_t)b * CO_ + oo + 0) * N_ + nn] = f2bf(v0);
                out[((size_t)b * CO_ + oo + 1) * N_ + nn] = f2bf(v1);
                out[((size_t)b * CO_ + oo + 2) * N_ + nn] = f2bf(v2);
                out[((size_t)b * CO_ + oo + 3) * N_ + nn] = f2bf(v3);
            }
        }
        // reduce over the 16 col-lanes (reads valid at col==0), write block partials
        #pragma unroll
        for (int off = 1; off < 16; off <<= 1) {
            s0 += __shfl_down(s0, off); q0 += __shfl_down(q0, off);
            s1 += __shfl_down(s1, off); q1 += __shfl_down(q1, off);
            s2 += __shfl_down(s2, off); q2 += __shfl_down(q2, off);
            s3 += __shfl_down(s3, off); q3 += __shfl_down(q3, off);
        }
        if (col == 0) {
            float* ps = psum + (size_t)prow * CO_ + oo;
            float* pq = psq  + (size_t)prow * CO_ + oo;
            ps[0] = s0; ps[1] = s1; ps[2] = s2; ps[3] = s3;
            pq[0] = q0; pq[1] = q1; pq[2] = q2; pq[3] = q3;
        }
    }
}

// ---------- reduce block partials + compute BN scale/shift (shared, deterministic) ----------
__global__ __launch_bounds__(256) void bn_reduce_kernel(
    const float* __restrict__ psum, const float* __restrict__ psq,
    const float* __restrict__ gamma, const float* __restrict__ beta,
    float* __restrict__ scale, float* __restrict__ shift)
{
    __shared__ float ls[4][64], lq[4][64];
    int l = threadIdx.x & 63;
    int seg = threadIdx.x >> 6;
    int ch = blockIdx.x * 64 + l;           // grid 4
    float s = 0.f, q = 0.f;
    for (int r = seg * 256; r < seg * 256 + 256; ++r) {
        s += psum[(size_t)r * CO_ + ch];
        q += psq [(size_t)r * CO_ + ch];
    }
    ls[seg][l] = s; lq[seg][l] = q;
    __syncthreads();
    if (seg == 0) {
        s = ls[0][l] + ls[1][l] + ls[2][l] + ls[3][l];
        q = lq[0][l] + lq[1][l] + lq[2][l] + lq[3][l];
        const float inv = 1.0f / 65536.0f;
        float m = s * inv;
        float var = fmaxf(q * inv - m * m, 0.f);
        float sc = gamma[ch] / sqrtf(var + 1e-5f);
        scale[ch] = sc;
        shift[ch] = beta[ch] - m * sc;
    }
}

// ---------- in-place: x2 = gelu(scale*y + shift) + te2, layout (B,N,256) bf16 ----------
__global__ __launch_bounds__(256) void apply1_kernel(
    unsigned short* __restrict__ y, const float* __restrict__ scale,
    const float* __restrict__ shift, const float* __restrict__ te2)
{
    __shared__ float ssc[CO_], ssh[CO_], ste[CO_];
    int b = blockIdx.x >> 10;
    int t = threadIdx.x;
    ssc[t] = scale[t]; ssh[t] = shift[t]; ste[t] = te2[b * CO_ + t];
    __syncthreads();
    int g = blockIdx.x * 256 + t;
    int row = g >> 5;
    int og = (g & 31) * 8;
    unsigned short* p = y + (size_t)row * CO_ + og;
    union { short8 v; unsigned short u[8]; } in, op;
    in.v = *(short8*)p;
    #pragma unroll
    for (int jj = 0; jj < 8; ++jj) {
        int o = og + jj;
        op.u[jj] = f2bf(gelu_f(ssc[o] * bf2f(in.u[jj]) + ssh[o]) + ste[o]);
    }
    *(short8*)p = op.v;
}

// ---------- final: out = gelu(scale*z + shift), layout (B,256,N), fp32 out ----------
__global__ __launch_bounds__(256) void final_kernel(
    const unsigned short* __restrict__ z, const float* __restrict__ scale,
    const float* __restrict__ shift, float* __restrict__ out)
{
    int g = blockIdx.x * 256 + threadIdx.x;
    size_t e = (size_t)g * 8;
    int row = (int)(e >> 13);
    int o = row & (CO_ - 1);
    float sc = scale[o], sh = shift[o];
    union { short8 v; unsigned short u[8]; } in;
    in.v = *(const short8*)&z[e];
    float vo[8];
    #pragma unroll
    for (int jj = 0; jj < 8; ++jj)
        vo[jj] = gelu_f(sc * bf2f(in.u[jj]) + sh);
    *(float4*)&out[e]     = make_float4(vo[0], vo[1], vo[2], vo[3]);
    *(float4*)&out[e + 4] = make_float4(vo[4], vo[5], vo[6], vo[7]);
}

// ---------- launch ----------
extern "C" void kernel_launch(void* const* d_in, const int* in_sizes, int n_in,
                              void* d_out, int out_size, void* d_ws, size_t ws_size,
                              hipStream_t stream)
{
    (void)in_sizes; (void)n_in; (void)out_size; (void)ws_size;
    const float* xyz1    = (const float*)d_in[0];
    const float* xyz2    = (const float*)d_in[1];
    const float* points1 = (const float*)d_in[2];
    const float* points2 = (const float*)d_in[3];
    const float* t_embed = (const float*)d_in[4];
    const float* w_t1    = (const float*)d_in[5];
    const float* b_t1    = (const float*)d_in[6];
    const float* w_c1    = (const float*)d_in[7];
    const float* b_c1    = (const float*)d_in[8];
    const float* g1      = (const float*)d_in[9];
    const float* be1     = (const float*)d_in[10];
    const float* w_t2    = (const float*)d_in[11];
    const float* b_t2    = (const float*)d_in[12];
    const float* w_c2    = (const float*)d_in[13];
    const float* b_c2    = (const float*)d_in[14];
    const float* g2      = (const float*)d_in[15];
    const float* be2     = (const float*)d_in[16];

    char* w = (char*)d_ws;
    float* te1        = (float*)(w + OFF_TE1);
    float* te2        = (float*)(w + OFF_TE2);
    float* scale1     = (float*)(w + OFF_BN1);
    float* shift1     = scale1 + 256;
    float* scale2     = (float*)(w + OFF_BN2);
    float* shift2     = scale2 + 256;
    int*   idx        = (int*)(w + OFF_IDX);
    float* wts        = (float*)(w + OFF_WTS);
    unsigned short* wc1 = (unsigned short*)(w + OFF_WC1);
    unsigned short* wc2 = (unsigned short*)(w + OFF_WC2);
    unsigned short* p2t = (unsigned short*)(w + OFF_P2T);
    float* pd         = (float*)(w + OFF_PD);
    int*   pi         = (int*)(w + OFF_PI);
    float* psum       = (float*)(w + OFF_PS);
    float* psq        = (float*)(w + OFF_PQ);
    unsigned short* X1  = (unsigned short*)(w + OFF_X1);
    unsigned short* Z   = (unsigned short*)(w + OFF_X1);
    unsigned short* Y   = (unsigned short*)(w + OFF_Y);
    float* out = (float*)d_out;

    hipLaunchKernelGGL(wcvt_kernel, dim3(CIN_ * CO_ / 256), dim3(256), 0, stream,
                       w_c1, w_c2, wc1, wc2);
    hipLaunchKernelGGL(te_kernel, dim3(B_), dim3(640), 0, stream,
                       t_embed, w_t1, b_t1, w_t2, b_t2, te1, te2);
    hipLaunchKernelGGL(knn_part_kernel, dim3(N_ / KQB, KCH, B_), dim3(256), 0, stream,
                       xyz1, xyz2, pd, pi);
    hipLaunchKernelGGL(knn_merge_kernel, dim3(B_ * N_ / 256), dim3(256), 0, stream,
                       pd, pi, idx, wts);
    hipLaunchKernelGGL(transpose_p2, dim3(S_ / 32, C2_ / 32, B_), dim3(32, 8), 0, stream,
                       points2, p2t);
    hipLaunchKernelGGL(build_x1_kernel, dim3(N_ / 128, B_), dim3(384), 0, stream,
                       points1, p2t, idx, wts, te1, X1);
    hipLaunchKernelGGL((gemm_bt<CIN_, 0>), dim3(N_ / 128, CO_ / 128, B_), dim3(256), 0, stream,
                       wc1, X1, b_c1, Y, psum, psq);
    hipLaunchKernelGGL(bn_reduce_kernel, dim3(4), dim3(256), 0, stream,
                       psum, psq, g1, be1, scale1, shift1);
    hipLaunchKernelGGL(apply1_kernel, dim3(8192), dim3(256), 0, stream,
                       Y, scale1, shift1, te2);
    hipLaunchKernelGGL((gemm_bt<CO_, 1>), dim3(N_ / 128, CO_ / 128, B_), dim3(256), 0, stream,
                       wc2, Y, b_c2, Z, psum, psq);
    hipLaunchKernelGGL(bn_reduce_kernel, dim3(4), dim3(256), 0, stream,
                       psum, psq, g2, be2, scale2, shift2);
    hipLaunchKernelGGL(final_kernel, dim3(8192), dim3(256), 0, stream,
                       Z, scale2, shift2, out);
}

// Round 6
// 368.360 us; speedup vs baseline: 1.1249x; 1.1249x over previous
//
#include <hip/hip_runtime.h>
#include <cfloat>
#include <cmath>

#define B_   8
#define N_   8192
#define S_   2048
#define C1_  128
#define C2_  256
#define T_   256
#define CIN_ 384
#define CO_  256

#define KCH  8           // knn S-chunks
#define KCS  (S_ / KCH)  // 256 candidates per chunk
#define KQB  512         // queries per knn block (256 thr x 2 queries)

typedef __attribute__((ext_vector_type(8))) short short8;
typedef __attribute__((ext_vector_type(4))) float f32x4;

// ---------- helpers ----------
__device__ __forceinline__ float bf2f(unsigned short u) {
    union { unsigned int i; float f; } v; v.i = ((unsigned int)u) << 16; return v.f;
}
__device__ __forceinline__ unsigned short f2bf(float f) {
    union { float f; unsigned int i; } v; v.f = f;
    unsigned int i = v.i;
    unsigned int r = i + 0x7FFFu + ((i >> 16) & 1u);   // RNE
    return (unsigned short)(r >> 16);
}
__device__ __forceinline__ float gelu_f(float x) {
    return 0.5f * x * (1.0f + erff(x * 0.70710678118654752440f));
}
__device__ __forceinline__ void async16(const void* g, void* l) {
    __builtin_amdgcn_global_load_lds((const __attribute__((address_space(1))) void*)g,
                                     (__attribute__((address_space(3))) void*)l, 16, 0, 0);
}

// ---------- ws layout (bytes) ----------
#define OFF_TE1   0u
#define OFF_TE2   16384u
#define OFF_BN1   28672u      // scale1(1024) shift1(1024)
#define OFF_BN2   30720u
#define OFF_IDX   32768u      // 65536*3*4 = 786432
#define OFF_WTS   819200u     // 786432
#define OFF_WC1   1605632u    // 98304*2
#define OFF_WC2   1802240u    // 65536*2  (ends 1933312)
#define OFF_P2T   2097152u    // 8*2048*256*2 = 8388608 (bf16)
#define OFF_X1    10485760u   // 8*8192*384*2 = 50331648 (bf16; Z + knn partials reuse)
#define OFF_Y     60817408u   // 8*8192*256*2 = 33554432 (bf16)
// transient tenants:
#define OFF_PD    OFF_X1                    // knn dist partials (dead before X1 write)
#define OFF_PI    (OFF_X1 + 6291456u)
#define OFF_PS    OFF_P2T                   // gemm stat partials [256ch][1024row] = 1 MB
#define OFF_PQ    (OFF_P2T + 1048576u)      // 1 MB (p2t dead by gemm time)

// ---------- weight fp32 -> bf16 ----------
__global__ __launch_bounds__(256) void wcvt_kernel(
    const float* __restrict__ w1, const float* __restrict__ w2,
    unsigned short* __restrict__ o1, unsigned short* __restrict__ o2)
{
    int g = blockIdx.x * 256 + threadIdx.x;
    o1[g] = f2bf(w1[g]);
    if (g < CO_ * CO_) o2[g] = f2bf(w2[g]);
}

// ---------- te1/te2 ----------
__global__ __launch_bounds__(640) void te_kernel(
    const float* __restrict__ t_embed,
    const float* __restrict__ w_t1, const float* __restrict__ b_t1,
    const float* __restrict__ w_t2, const float* __restrict__ b_t2,
    float* __restrict__ te1, float* __restrict__ te2)
{
    __shared__ float gt[T_];
    int b = blockIdx.x, t = threadIdx.x;
    if (t < T_) gt[t] = gelu_f(t_embed[b * T_ + t]);
    __syncthreads();
    if (t < CIN_) {
        const float* w = w_t1 + t * T_;
        float s = 0.f;
        for (int k = 0; k < T_; ++k) s += gt[k] * w[k];
        te1[b * CIN_ + t] = s + b_t1[t];
    } else {
        int o = t - CIN_;
        const float* w = w_t2 + o * T_;
        float s = 0.f;
        for (int k = 0; k < T_; ++k) s += gt[k] * w[k];
        te2[b * CO_ + o] = s + b_t2[o];
    }
}

// ---------- 3-NN partials: per S-chunk top-3, branch-free cswap ----------
__global__ __launch_bounds__(256) void knn_part_kernel(
    const float* __restrict__ xyz1, const float* __restrict__ xyz2,
    float* __restrict__ pd, int* __restrict__ pi)
{
    __shared__ float4 sp[KCS];   // 4 KB
    int b = blockIdx.z, ch = blockIdx.y, tid = threadIdx.x;
    int s0 = ch * KCS;
    {
        int gs = s0 + tid;
        float x = xyz2[(b * S_ + gs) * 3 + 0];
        float y = xyz2[(b * S_ + gs) * 3 + 1];
        float z = xyz2[(b * S_ + gs) * 3 + 2];
        sp[tid] = make_float4(x, y, z, x * x + y * y + z * z);
    }
    __syncthreads();

    float nx[2], ny[2], nz[2], nn[2];
    float d1[2], d2[2], d3[2];
    int   i1[2], i2[2], i3[2];
    #pragma unroll
    for (int qq = 0; qq < 2; ++qq) {
        int n = blockIdx.x * KQB + qq * 256 + tid;
        float x1 = xyz1[(b * N_ + n) * 3 + 0];
        float y1 = xyz1[(b * N_ + n) * 3 + 1];
        float z1 = xyz1[(b * N_ + n) * 3 + 2];
        nn[qq] = x1 * x1 + y1 * y1 + z1 * z1;
        nx[qq] = -2.0f * x1; ny[qq] = -2.0f * y1; nz[qq] = -2.0f * z1;
        d1[qq] = FLT_MAX; d2[qq] = FLT_MAX; d3[qq] = FLT_MAX;
        i1[qq] = 0; i2[qq] = 0; i3[qq] = 0;
    }

    for (int s = 0; s < KCS; s += 4) {
        #pragma unroll
        for (int u = 0; u < 4; ++u) {
            float4 p = sp[s + u];
            int gi = s0 + s + u;
            #pragma unroll
            for (int qq = 0; qq < 2; ++qq) {
                float d = fmaf(nx[qq], p.x,
                          fmaf(ny[qq], p.y,
                          fmaf(nz[qq], p.z, nn[qq] + p.w)));
                bool c3 = d < d3[qq];
                i3[qq] = c3 ? gi : i3[qq];
                d3[qq] = fminf(d3[qq], d);
                bool c2 = d3[qq] < d2[qq];
                float lo2 = fminf(d2[qq], d3[qq]);
                float hi2 = fmaxf(d2[qq], d3[qq]);
                int t2 = c2 ? i3[qq] : i2[qq];
                int t3 = c2 ? i2[qq] : i3[qq];
                d2[qq] = lo2; d3[qq] = hi2; i2[qq] = t2; i3[qq] = t3;
                bool c1 = d2[qq] < d1[qq];
                float lo1 = fminf(d1[qq], d2[qq]);
                float hi1 = fmaxf(d1[qq], d2[qq]);
                int t1  = c1 ? i2[qq] : i1[qq];
                int t2b = c1 ? i1[qq] : i2[qq];
                d1[qq] = lo1; d2[qq] = hi1; i1[qq] = t1; i2[qq] = t2b;
            }
        }
    }

    #pragma unroll
    for (int qq = 0; qq < 2; ++qq) {
        int n = blockIdx.x * KQB + qq * 256 + tid;
        size_t pb = (((size_t)b * KCH + ch) * N_ + n) * 3;
        pd[pb + 0] = d1[qq]; pd[pb + 1] = d2[qq]; pd[pb + 2] = d3[qq];
        pi[pb + 0] = i1[qq]; pi[pb + 1] = i2[qq]; pi[pb + 2] = i3[qq];
    }
}

// ---------- merge chunk partials -> idx/wts ----------
__global__ __launch_bounds__(256) void knn_merge_kernel(
    const float* __restrict__ pd, const int* __restrict__ pi,
    int* __restrict__ idx, float* __restrict__ wts)
{
    int g = blockIdx.x * 256 + threadIdx.x;   // 65536
    int b = g >> 13, n = g & (N_ - 1);
    float d1 = FLT_MAX, d2 = FLT_MAX, d3 = FLT_MAX;
    int   i1 = 0, i2 = 0, i3 = 0;
    for (int ch = 0; ch < KCH; ++ch) {
        size_t pb = (((size_t)b * KCH + ch) * N_ + n) * 3;
        #pragma unroll
        for (int k = 0; k < 3; ++k) {
            float d = pd[pb + k];
            int   s = pi[pb + k];
            if (d < d3) {
                if (d < d2) {
                    d3 = d2; i3 = i2;
                    if (d < d1) { d2 = d1; i2 = i1; d1 = d; i1 = s; }
                    else        { d2 = d;  i2 = s; }
                } else { d3 = d; i3 = s; }
            }
        }
    }
    float r1 = 1.0f / (d1 + 1e-8f);
    float r2 = 1.0f / (d2 + 1e-8f);
    float r3 = 1.0f / (d3 + 1e-8f);
    float rs = 1.0f / (r1 + r2 + r3);
    size_t base = (size_t)g * 3;
    idx[base] = i1; idx[base + 1] = i2; idx[base + 2] = i3;
    wts[base] = r1 * rs; wts[base + 1] = r2 * rs; wts[base + 2] = r3 * rs;
}

// ---------- transpose points2 (B,C2,S) fp32 -> (B,S,C2) bf16 ----------
__global__ __launch_bounds__(256) void transpose_p2(
    const float* __restrict__ p2, unsigned short* __restrict__ p2t)
{
    __shared__ unsigned short tile[32][33];
    int b = blockIdx.z, s0 = blockIdx.x * 32, c0 = blockIdx.y * 32;
    #pragma unroll
    for (int j = 0; j < 4; ++j) {
        int c = threadIdx.y + j * 8;
        tile[c][threadIdx.x] = f2bf(p2[((size_t)b * C2_ + c0 + c) * S_ + s0 + threadIdx.x]);
    }
    __syncthreads();
    #pragma unroll
    for (int j = 0; j < 4; ++j) {
        int s = threadIdx.y + j * 8;
        p2t[((size_t)b * S_ + s0 + s) * C2_ + c0 + threadIdx.x] = tile[threadIdx.x][s];
    }
}

// ---------- transpose points1 (B,128,N) fp32 + te1 -> X1[:, 0:128] bf16 ----------
__global__ __launch_bounds__(256) void transpose_p1(
    const float* __restrict__ p1, const float* __restrict__ te1,
    unsigned short* __restrict__ X1)
{
    __shared__ unsigned short tile[32][33];
    int b = blockIdx.z, n0 = blockIdx.x * 32, c0 = blockIdx.y * 32;
    const float* te = te1 + b * CIN_;
    #pragma unroll
    for (int j = 0; j < 4; ++j) {
        int c = threadIdx.y + j * 8;
        tile[c][threadIdx.x] =
            f2bf(p1[((size_t)b * C1_ + c0 + c) * N_ + n0 + threadIdx.x] + te[c0 + c]);
    }
    __syncthreads();
    #pragma unroll
    for (int j = 0; j < 4; ++j) {
        int n = threadIdx.y + j * 8;
        X1[((size_t)b * N_ + n0 + n) * CIN_ + c0 + threadIdx.x] = tile[threadIdx.x][n];
    }
}

// ---------- interp: X1[:, 128:384] = weighted p2t gather + te1 ----------
// 8 rows per block; each 32-lane half-wave does one row, lanes cover channels.
__global__ __launch_bounds__(256) void interp_kernel(
    const unsigned short* __restrict__ p2t,
    const int* __restrict__ idx, const float* __restrict__ wts,
    const float* __restrict__ te1, unsigned short* __restrict__ X1)
{
    __shared__ float ste[C2_];
    int tid = threadIdx.x;
    int b = blockIdx.x >> 10;                 // 1024 blocks per batch
    ste[tid] = te1[b * CIN_ + C1_ + tid];
    __syncthreads();
    int half = tid >> 5;                      // 0..7: row within block
    int chunk = tid & 31;                     // 16B chunk (8 channels)
    int gr = blockIdx.x * 8 + half;           // global row (b*N + n)
    size_t base3 = (size_t)gr * 3;
    int j0 = idx[base3], j1 = idx[base3 + 1], j2 = idx[base3 + 2];
    float w0 = wts[base3], w1 = wts[base3 + 1], w2 = wts[base3 + 2];
    int co = chunk * 8;
    const unsigned short* r0 = p2t + ((size_t)b * S_ + j0) * C2_ + co;
    const unsigned short* r1 = p2t + ((size_t)b * S_ + j1) * C2_ + co;
    const unsigned short* r2 = p2t + ((size_t)b * S_ + j2) * C2_ + co;
    union { short8 v; unsigned short u[8]; } a0, a1, a2, pk;
    a0.v = *(const short8*)r0;
    a1.v = *(const short8*)r1;
    a2.v = *(const short8*)r2;
    #pragma unroll
    for (int jj = 0; jj < 8; ++jj) {
        float v = w0 * bf2f(a0.u[jj]) + w1 * bf2f(a1.u[jj]) + w2 * bf2f(a2.u[jj])
                + ste[co + jj];
        pk.u[jj] = f2bf(v);
    }
    *(short8*)&X1[(size_t)gr * CIN_ + C1_ + co] = pk.v;
}

// ---------- GEMM (m97-style, B^T input) + fused BN-stat partials ----------
// Partials layout: psum/psq [256 ch][1024 rows]; row p = (b*64 + bx)*2 + wm.
template <int K, int MODE>
__global__ __launch_bounds__(256) void gemm_bt(
    const unsigned short* __restrict__ A,
    const unsigned short* __restrict__ X,
    const float* __restrict__ bias,
    unsigned short* __restrict__ out,
    float* __restrict__ psum, float* __restrict__ psq)
{
    __shared__ unsigned short sA[128 * 64];
    __shared__ unsigned short sB[128 * 64];
    const int tid = threadIdx.x;
    const int lane = tid & 63, wave = tid >> 6;
    const int wo = wave >> 1, wm = wave & 1;
    const int quad = lane >> 4, col = lane & 15;
    const int b = blockIdx.z;
    const int o0 = blockIdx.y * 128;
    const int n0 = blockIdx.x * 128;
    const unsigned short* Xb = X + (size_t)b * N_ * K;
    const int prow = ((b << 6) + blockIdx.x) * 2 + wm;

    f32x4 acc[4][4];
    #pragma unroll
    for (int i = 0; i < 4; ++i)
        #pragma unroll
        for (int j = 0; j < 4; ++j) acc[i][j] = (f32x4){0.f, 0.f, 0.f, 0.f};

    for (int k0 = 0; k0 < K; k0 += 64) {
        #pragma unroll
        for (int i = 0; i < 4; ++i) {
            int chunk = i * 256 + tid;
            int row = chunk >> 3, c8 = chunk & 7;
            async16(&A [(o0 + row) * K + k0 + c8 * 8], &sA[chunk * 8]);
            async16(&Xb[(size_t)(n0 + row) * K + k0 + c8 * 8], &sB[chunk * 8]);
        }
        __syncthreads();
        #pragma unroll
        for (int kk = 0; kk < 64; kk += 32) {
            short8 af[4], bfr[4];
            #pragma unroll
            for (int i = 0; i < 4; ++i)
                af[i] = *(const short8*)&sA[(wo * 64 + i * 16 + col) * 64 + kk + quad * 8];
            #pragma unroll
            for (int j = 0; j < 4; ++j)
                bfr[j] = *(const short8*)&sB[(wm * 64 + j * 16 + col) * 64 + kk + quad * 8];
            #pragma unroll
            for (int i = 0; i < 4; ++i)
                #pragma unroll
                for (int j = 0; j < 4; ++j)
                    acc[i][j] = __builtin_amdgcn_mfma_f32_16x16x32_bf16(af[i], bfr[j], acc[i][j], 0, 0, 0);
        }
        __syncthreads();
    }

    #pragma unroll
    for (int i = 0; i < 4; ++i) {
        int oo = o0 + wo * 64 + i * 16 + quad * 4;
        float bv0 = bias[oo + 0], bv1 = bias[oo + 1];
        float bv2 = bias[oo + 2], bv3 = bias[oo + 3];
        float s0 = 0.f, s1 = 0.f, s2 = 0.f, s3 = 0.f;
        float q0 = 0.f, q1 = 0.f, q2 = 0.f, q3 = 0.f;
        #pragma unroll
        for (int j = 0; j < 4; ++j) {
            int nn = n0 + wm * 64 + j * 16 + col;
            float v0 = acc[i][j][0] + bv0, v1 = acc[i][j][1] + bv1;
            float v2 = acc[i][j][2] + bv2, v3 = acc[i][j][3] + bv3;
            s0 += v0; q0 += v0 * v0; s1 += v1; q1 += v1 * v1;
            s2 += v2; q2 += v2 * v2; s3 += v3; q3 += v3 * v3;
            if (MODE == 0) {
                union { unsigned short u[4]; uint2 p; } pk;
                pk.u[0] = f2bf(v0); pk.u[1] = f2bf(v1);
                pk.u[2] = f2bf(v2); pk.u[3] = f2bf(v3);
                *(uint2*)&out[((size_t)b * N_ + nn) * CO_ + oo] = pk.p;
            } else {
                out[((size_t)b * CO_ + oo + 0) * N_ + nn] = f2bf(v0);
                out[((size_t)b * CO_ + oo + 1) * N_ + nn] = f2bf(v1);
                out[((size_t)b * CO_ + oo + 2) * N_ + nn] = f2bf(v2);
                out[((size_t)b * CO_ + oo + 3) * N_ + nn] = f2bf(v3);
            }
        }
        #pragma unroll
        for (int off = 1; off < 16; off <<= 1) {
            s0 += __shfl_down(s0, off); q0 += __shfl_down(q0, off);
            s1 += __shfl_down(s1, off); q1 += __shfl_down(q1, off);
            s2 += __shfl_down(s2, off); q2 += __shfl_down(q2, off);
            s3 += __shfl_down(s3, off); q3 += __shfl_down(q3, off);
        }
        if (col == 0) {
            float* ps = psum + (size_t)oo * 1024 + prow;
            float* pq = psq  + (size_t)oo * 1024 + prow;
            ps[0] = s0; ps[1024] = s1; ps[2048] = s2; ps[3072] = s3;
            pq[0] = q0; pq[1024] = q1; pq[2048] = q2; pq[3072] = q3;
        }
    }
}

// ---------- reduce partials (ch-major, coalesced) + BN scale/shift ----------
__global__ __launch_bounds__(256) void bn_reduce_kernel(
    const float* __restrict__ psum, const float* __restrict__ psq,
    const float* __restrict__ gamma, const float* __restrict__ beta,
    float* __restrict__ scale, float* __restrict__ shift)
{
    int ch = blockIdx.x * 8 + (threadIdx.x >> 5);   // grid 32
    int l = threadIdx.x & 31;
    float s = 0.f, q = 0.f;
    for (int r = l; r < 1024; r += 32) {
        s += psum[(size_t)ch * 1024 + r];
        q += psq [(size_t)ch * 1024 + r];
    }
    #pragma unroll
    for (int off = 16; off > 0; off >>= 1) {
        s += __shfl_down(s, off, 32);
        q += __shfl_down(q, off, 32);
    }
    if (l == 0) {
        const float inv = 1.0f / 65536.0f;
        float m = s * inv;
        float var = fmaxf(q * inv - m * m, 0.f);
        float sc = gamma[ch] / sqrtf(var + 1e-5f);
        scale[ch] = sc;
        shift[ch] = beta[ch] - m * sc;
    }
}

// ---------- in-place: x2 = gelu(scale*y + shift) + te2, layout (B,N,256) bf16 ----------
__global__ __launch_bounds__(256) void apply1_kernel(
    unsigned short* __restrict__ y, const float* __restrict__ scale,
    const float* __restrict__ shift, const float* __restrict__ te2)
{
    __shared__ float ssc[CO_], ssh[CO_], ste[CO_];
    int b = blockIdx.x >> 10;
    int t = threadIdx.x;
    ssc[t] = scale[t]; ssh[t] = shift[t]; ste[t] = te2[b * CO_ + t];
    __syncthreads();
    int g = blockIdx.x * 256 + t;
    int row = g >> 5;
    int og = (g & 31) * 8;
    unsigned short* p = y + (size_t)row * CO_ + og;
    union { short8 v; unsigned short u[8]; } in, op;
    in.v = *(short8*)p;
    #pragma unroll
    for (int jj = 0; jj < 8; ++jj) {
        int o = og + jj;
        op.u[jj] = f2bf(gelu_f(ssc[o] * bf2f(in.u[jj]) + ssh[o]) + ste[o]);
    }
    *(short8*)p = op.v;
}

// ---------- final: out = gelu(scale*z + shift), layout (B,256,N), fp32 out ----------
__global__ __launch_bounds__(256) void final_kernel(
    const unsigned short* __restrict__ z, const float* __restrict__ scale,
    const float* __restrict__ shift, float* __restrict__ out)
{
    int g = blockIdx.x * 256 + threadIdx.x;
    size_t e = (size_t)g * 8;
    int row = (int)(e >> 13);
    int o = row & (CO_ - 1);
    float sc = scale[o], sh = shift[o];
    union { short8 v; unsigned short u[8]; } in;
    in.v = *(const short8*)&z[e];
    float vo[8];
    #pragma unroll
    for (int jj = 0; jj < 8; ++jj)
        vo[jj] = gelu_f(sc * bf2f(in.u[jj]) + sh);
    *(float4*)&out[e]     = make_float4(vo[0], vo[1], vo[2], vo[3]);
    *(float4*)&out[e + 4] = make_float4(vo[4], vo[5], vo[6], vo[7]);
}

// ---------- launch ----------
extern "C" void kernel_launch(void* const* d_in, const int* in_sizes, int n_in,
                              void* d_out, int out_size, void* d_ws, size_t ws_size,
                              hipStream_t stream)
{
    (void)in_sizes; (void)n_in; (void)out_size; (void)ws_size;
    const float* xyz1    = (const float*)d_in[0];
    const float* xyz2    = (const float*)d_in[1];
    const float* points1 = (const float*)d_in[2];
    const float* points2 = (const float*)d_in[3];
    const float* t_embed = (const float*)d_in[4];
    const float* w_t1    = (const float*)d_in[5];
    const float* b_t1    = (const float*)d_in[6];
    const float* w_c1    = (const float*)d_in[7];
    const float* b_c1    = (const float*)d_in[8];
    const float* g1      = (const float*)d_in[9];
    const float* be1     = (const float*)d_in[10];
    const float* w_t2    = (const float*)d_in[11];
    const float* b_t2    = (const float*)d_in[12];
    const float* w_c2    = (const float*)d_in[13];
    const float* b_c2    = (const float*)d_in[14];
    const float* g2      = (const float*)d_in[15];
    const float* be2     = (const float*)d_in[16];

    char* w = (char*)d_ws;
    float* te1        = (float*)(w + OFF_TE1);
    float* te2        = (float*)(w + OFF_TE2);
    float* scale1     = (float*)(w + OFF_BN1);
    float* shift1     = scale1 + 256;
    float* scale2     = (float*)(w + OFF_BN2);
    float* shift2     = scale2 + 256;
    int*   idx        = (int*)(w + OFF_IDX);
    float* wts        = (float*)(w + OFF_WTS);
    unsigned short* wc1 = (unsigned short*)(w + OFF_WC1);
    unsigned short* wc2 = (unsigned short*)(w + OFF_WC2);
    unsigned short* p2t = (unsigned short*)(w + OFF_P2T);
    float* pd         = (float*)(w + OFF_PD);
    int*   pi         = (int*)(w + OFF_PI);
    float* psum       = (float*)(w + OFF_PS);
    float* psq        = (float*)(w + OFF_PQ);
    unsigned short* X1  = (unsigned short*)(w + OFF_X1);
    unsigned short* Z   = (unsigned short*)(w + OFF_X1);
    unsigned short* Y   = (unsigned short*)(w + OFF_Y);
    float* out = (float*)d_out;

    hipLaunchKernelGGL(wcvt_kernel, dim3(CIN_ * CO_ / 256), dim3(256), 0, stream,
                       w_c1, w_c2, wc1, wc2);
    hipLaunchKernelGGL(te_kernel, dim3(B_), dim3(640), 0, stream,
                       t_embed, w_t1, b_t1, w_t2, b_t2, te1, te2);
    hipLaunchKernelGGL(knn_part_kernel, dim3(N_ / KQB, KCH, B_), dim3(256), 0, stream,
                       xyz1, xyz2, pd, pi);
    hipLaunchKernelGGL(knn_merge_kernel, dim3(B_ * N_ / 256), dim3(256), 0, stream,
                       pd, pi, idx, wts);
    hipLaunchKernelGGL(transpose_p2, dim3(S_ / 32, C2_ / 32, B_), dim3(32, 8), 0, stream,
                       points2, p2t);
    // X1 region becomes writable only after knn_merge has consumed pd/pi
    hipLaunchKernelGGL(transpose_p1, dim3(N_ / 32, C1_ / 32, B_), dim3(32, 8), 0, stream,
                       points1, te1, X1);
    hipLaunchKernelGGL(interp_kernel, dim3(B_ * N_ / 8), dim3(256), 0, stream,
                       p2t, idx, wts, te1, X1);
    hipLaunchKernelGGL((gemm_bt<CIN_, 0>), dim3(N_ / 128, CO_ / 128, B_), dim3(256), 0, stream,
                       wc1, X1, b_c1, Y, psum, psq);
    hipLaunchKernelGGL(bn_reduce_kernel, dim3(32), dim3(256), 0, stream,
                       psum, psq, g1, be1, scale1, shift1);
    hipLaunchKernelGGL(apply1_kernel, dim3(8192), dim3(256), 0, stream,
                       Y, scale1, shift1, te2);
    hipLaunchKernelGGL((gemm_bt<CO_, 1>), dim3(N_ / 128, CO_ / 128, B_), dim3(256), 0, stream,
                       wc2, Y, b_c2, Z, psum, psq);
    hipLaunchKernelGGL(bn_reduce_kernel, dim3(32), dim3(256), 0, stream,
                       psum, psq, g2, be2, scale2, shift2);
    hipLaunchKernelGGL(final_kernel, dim3(8192), dim3(256), 0, stream,
                       Z, scale2, shift2, out);
}